// Round 1
// baseline (523.709 us; speedup 1.0000x reference)
//
#include <hip/hip_runtime.h>
#include <stdint.h>

// ---------------- problem constants ----------------
constexpr int B_  = 8, N_ = 20, HM = 64, WM = 64, A_ = 42, CIN = 256, HIDN = 512;
constexpr int M_  = HM * WM * A_;          // 172032 anchors per image
constexpr int NA  = B_ * M_;               // 1376256 total anchors
constexpr int HALF = NA / 2;               // 688128 (threefry pairing)
constexpr int KK  = CIN * 9;               // 2304 (im2col K)
constexpr float NEG_T = 0.3f, POS_T = 0.5f;

constexpr int NBINS  = 65536;
constexpr int MAXPOS = 8192, MAXSEL = 8192, MAXTIE = 4096, MAXPIX = 1024;

// ---------------- workspace layout (bytes) ----------------
constexpr size_t OFF_HIST  = 0;                                   // u32[65536]
constexpr size_t OFF_CTRL  = OFF_HIST + (size_t)NBINS * 4;        // u32[64] (+f32 accums at [16..18])
constexpr size_t OFF_MAXGT = OFF_CTRL + 256;                      // f32-bits int[160]
constexpr size_t OFF_GSAFE = OFF_MAXGT + 160 * 4;                 // f32[160*4]
constexpr size_t OFF_AREAG = OFF_GSAFE + 160 * 4 * 4;             // f32[160]
constexpr size_t OFF_VALID = OFF_AREAG + 160 * 4;                 // u32[160]
constexpr size_t OFF_BASE  = OFF_VALID + 160 * 4;                 // f32[42*4] (pad to 192)
constexpr size_t OFF_NEED  = OFF_BASE + 192 * 4;                  // u8[B*4096]
constexpr size_t ZERO_END  = OFF_NEED + (size_t)B_ * 4096;        // memset region [0, ZERO_END)
constexpr size_t OFF_SLOT  = (ZERO_END + 255) & ~(size_t)255;     // i32[B*4096]
constexpr size_t OFF_PLIST = OFF_SLOT + (size_t)B_ * 4096 * 4;    // i32[MAXPIX]
constexpr size_t OFF_POSL  = OFF_PLIST + (size_t)MAXPIX * 4;      // i32[MAXPOS]
constexpr size_t OFF_SELL  = OFF_POSL + (size_t)MAXPOS * 4;       // i32[MAXSEL]
constexpr size_t OFF_TIE   = OFF_SELL + (size_t)MAXSEL * 4;       // u32[2*MAXTIE]
constexpr size_t OFF_FLAGS = OFF_TIE + (size_t)MAXTIE * 8;        // u8[NA]
constexpr size_t OFF_A2G   = OFF_FLAGS + (size_t)NA;              // u8[NA]
constexpr size_t OFF_UARR  = ((OFF_A2G + (size_t)NA) + 255) & ~(size_t)255; // u32[NA]
constexpr size_t OFF_HID   = OFF_UARR + (size_t)NA * 4;           // f32[MAXPIX*HIDN]  (memset)
constexpr size_t OFF_APATCH= OFF_HID + (size_t)MAXPIX * HIDN * 4; // f32[MAXPIX*KK]

// ctrl indices: 0 n_pos, 1 n_sel, 2 n_pix, 3 n_tie, 4 cutbin, 5 c_lt, 6 r, 7 ucut, 8 idxcut
// float accums (alias at ctrl+16): [0] cls_pos, [1] cls_neg, [2] reg_sum

// ---------------- helpers ----------------
__device__ __forceinline__ float iou_pair(float ay0, float ax0, float ay1, float ax1,
                                          float areaA, float g0, float g1, float g2, float g3,
                                          float areaG) {
#pragma clang fp contract(off)
  float ty = fmaxf(ay0, g0), tx = fmaxf(ax0, g1);
  float by = fminf(ay1, g2), bx = fminf(ax1, g3);
  float hy = by - ty; hy = fmaxf(hy, 0.f);
  float hx = bx - tx; hx = fmaxf(hx, 0.f);
  float inter = hy * hx;
  return inter / (areaA + areaG - inter);
}

__device__ __forceinline__ void anchor_box(const float* basef, int a, int y, int x,
                                           float& ay0, float& ax0, float& ay1, float& ax1,
                                           float& areaA) {
#pragma clang fp contract(off)
  double sy = 16.0 * (double)y, sx = 16.0 * (double)x;
  ay0 = (float)((double)basef[a * 4 + 0] + sy);
  ax0 = (float)((double)basef[a * 4 + 1] + sx);
  ay1 = (float)((double)basef[a * 4 + 2] + sy);
  ax1 = (float)((double)basef[a * 4 + 3] + sx);
  areaA = (ay1 - ay0) * (ax1 - ax0);
}

__device__ __forceinline__ float softplusf(float x) {
  return fmaxf(x, 0.f) + log1pf(expf(-fabsf(x)));
}

__device__ __forceinline__ float sl1(float d) {
  float ad = fabsf(d);
  return ad < 1.f ? 0.5f * ad * ad : ad - 0.5f;
}

__device__ __forceinline__ void tf_round(uint32_t& x0, uint32_t& x1, int r) {
  x0 += x1; x1 = (x1 << r) | (x1 >> (32 - r)); x1 ^= x0;
}
// jax threefry2x32 with key (0,7)
__device__ __forceinline__ void threefry(uint32_t c0, uint32_t c1, uint32_t& o0, uint32_t& o1) {
  const uint32_t k0 = 0u, k1 = 7u;
  const uint32_t k2 = k0 ^ k1 ^ 0x1BD11BDAu;
  uint32_t x0 = c0 + k0, x1 = c1 + k1;
  tf_round(x0, x1, 13); tf_round(x0, x1, 15); tf_round(x0, x1, 26); tf_round(x0, x1, 6);
  x0 += k1; x1 += k2 + 1u;
  tf_round(x0, x1, 17); tf_round(x0, x1, 29); tf_round(x0, x1, 16); tf_round(x0, x1, 24);
  x0 += k2; x1 += k0 + 2u;
  tf_round(x0, x1, 13); tf_round(x0, x1, 15); tf_round(x0, x1, 26); tf_round(x0, x1, 6);
  x0 += k0; x1 += k1 + 3u;
  tf_round(x0, x1, 17); tf_round(x0, x1, 29); tf_round(x0, x1, 16); tf_round(x0, x1, 24);
  x0 += k1; x1 += k2 + 4u;
  tf_round(x0, x1, 13); tf_round(x0, x1, 15); tf_round(x0, x1, 26); tf_round(x0, x1, 6);
  x0 += k2; x1 += k0 + 5u;
  o0 = x0; o1 = x1;
}

// ---------------- K0: base anchors + projected GT ----------------
__global__ void __launch_bounds__(256) k0_prep(const float* __restrict__ gt, char* ws) {
  int t = threadIdx.x;
  float* basef = (float*)(ws + OFF_BASE);
  if (t < 42) {
    const double SC[6] = {2.0, 2.5, 3.0, 3.5, 4.0, 5.0};
    const double RA[7] = {0.5, 1.5, 2.0, 2.5, 3.0, 3.5, 4.0};
    int si = t / 7, ri = t - si * 7;
    double h = 16.0 * SC[si] * sqrt(RA[ri]);
    double w = 16.0 * SC[si] * sqrt(1.0 / RA[ri]);
    basef[t * 4 + 0] = (float)(8.0 - h / 2.0);
    basef[t * 4 + 1] = (float)(8.0 - w / 2.0);
    basef[t * 4 + 2] = (float)(8.0 + h / 2.0);
    basef[t * 4 + 3] = (float)(8.0 + w / 2.0);
  }
  if (t < 160) {
#pragma clang fp contract(off)
    float* gs = (float*)(ws + OFF_GSAFE);
    float* ar = (float*)(ws + OFF_AREAG);
    unsigned* va = (unsigned*)(ws + OFF_VALID);
    float g4[4];
    for (int d = 0; d < 4; d++) {
      float v = gt[t * 4 + d];
      g4[d] = (v == -1.0f) ? -1.0f : v * 0.0625f;   // /16 exact
    }
    unsigned valid = (g4[0] >= 0.0f) ? 1u : 0u;
    if (!valid) { g4[0] = 0.f; g4[1] = 0.f; g4[2] = 1.f; g4[3] = 1.f; }
    gs[t * 4 + 0] = g4[0]; gs[t * 4 + 1] = g4[1];
    gs[t * 4 + 2] = g4[2]; gs[t * 4 + 3] = g4[3];
    ar[t] = (g4[2] - g4[0]) * (g4[3] - g4[1]);
    va[t] = valid;
  }
}

// ---------------- K1: per-GT max IoU over all anchors ----------------
__global__ void __launch_bounds__(256) k1_maxgt(char* ws) {
  int b = blockIdx.x / (M_ / 256);
  int i = blockIdx.x * 256 + threadIdx.x;
  int m = i - b * M_;
  int t = threadIdx.x;
  __shared__ float sg[80]; __shared__ float sarea[20]; __shared__ unsigned sval[20];
  __shared__ int smax[20]; __shared__ float sbase[168];
  if (t < 20) { sarea[t] = ((float*)(ws + OFF_AREAG))[b * 20 + t];
                sval[t] = ((unsigned*)(ws + OFF_VALID))[b * 20 + t]; smax[t] = 0; }
  if (t < 80)  sg[t] = ((float*)(ws + OFF_GSAFE))[b * 80 + t];
  if (t < 168) sbase[t] = ((float*)(ws + OFF_BASE))[t];
  __syncthreads();
  int pix = m / 42, a = m - pix * 42;
  int y = pix >> 6, x = pix & 63;
  float ay0, ax0, ay1, ax1, areaA;
  anchor_box(sbase, a, y, x, ay0, ax0, ay1, ax1, areaA);
  int lane = t & 63;
  for (int n = 0; n < 20; n++) {
    float io = 0.f;
    if (sval[n]) io = iou_pair(ay0, ax0, ay1, ax1, areaA,
                               sg[n * 4], sg[n * 4 + 1], sg[n * 4 + 2], sg[n * 4 + 3], sarea[n]);
    float v = io;
#pragma unroll
    for (int off = 32; off >= 1; off >>= 1) v = fmaxf(v, __shfl_xor(v, off, 64));
    if (lane == 0) atomicMax(&smax[n], __float_as_int(v));
  }
  __syncthreads();
  if (t < 20) atomicMax((int*)(ws + OFF_MAXGT) + b * 20 + t, smax[t]);
}

// ---------------- K2: per-anchor assignment ----------------
__global__ void __launch_bounds__(256) k2_assign(char* ws) {
  int b = blockIdx.x / (M_ / 256);
  int i = blockIdx.x * 256 + threadIdx.x;
  int m = i - b * M_;
  int t = threadIdx.x;
  __shared__ float sg[80]; __shared__ float sarea[20]; __shared__ unsigned sval[20];
  __shared__ float smg[20]; __shared__ float sbase[168];
  if (t < 20) { sarea[t] = ((float*)(ws + OFF_AREAG))[b * 20 + t];
                sval[t] = ((unsigned*)(ws + OFF_VALID))[b * 20 + t];
                smg[t] = __int_as_float(((int*)(ws + OFF_MAXGT))[b * 20 + t]); }
  if (t < 80)  sg[t] = ((float*)(ws + OFF_GSAFE))[b * 80 + t];
  if (t < 168) sbase[t] = ((float*)(ws + OFF_BASE))[t];
  __syncthreads();
  int pix = m / 42, a = m - pix * 42;
  int y = pix >> 6, x = pix & 63;
  float ay0, ax0, ay1, ax1, areaA;
  anchor_box(sbase, a, y, x, ay0, ax0, ay1, ax1, areaA);
  float best = -1.f; int arg = 0; bool pos = false;
  for (int n = 0; n < 20; n++) {
    float io = 0.f;
    if (sval[n]) io = iou_pair(ay0, ax0, ay1, ax1, areaA,
                               sg[n * 4], sg[n * 4 + 1], sg[n * 4 + 2], sg[n * 4 + 3], sarea[n]);
    if (io > best) { best = io; arg = n; }
    float mg = smg[n];
    pos = pos || ((io == mg) && (mg > 0.f)) || (io > POS_T);
  }
  bool neg = best < NEG_T;
  ((unsigned char*)(ws + OFF_FLAGS))[i] = (unsigned char)((pos ? 1 : 0) | (neg ? 2 : 0));
  ((unsigned char*)(ws + OFF_A2G))[i] = (unsigned char)arg;
  if (pos) {
    unsigned idx = atomicAdd((unsigned*)(ws + OFF_CTRL) + 0, 1u);
    if (idx < MAXPOS) ((int*)(ws + OFF_POSL))[idx] = i;
  }
}

// ---------------- K3a: threefry scores + histogram ----------------
__global__ void __launch_bounds__(256) k3a_scores(char* ws) {
  int p = blockIdx.x * 256 + threadIdx.x;   // [0, HALF)
  uint32_t o0, o1; threefry((uint32_t)p, (uint32_t)(p + HALF), o0, o1);
  uint32_t v0 = o0 >> 9, v1 = o1 >> 9;
  uint32_t* uarr = (uint32_t*)(ws + OFF_UARR);
  uarr[p] = v0; uarr[p + HALF] = v1;
  const unsigned char* flags = (const unsigned char*)(ws + OFF_FLAGS);
  unsigned* hist = (unsigned*)(ws + OFF_HIST);
  if (flags[p] & 2)        atomicAdd(&hist[v0 >> 7], 1u);
  if (flags[p + HALF] & 2) atomicAdd(&hist[v1 >> 7], 1u);
}

// ---------------- K3b: find cutoff bin ----------------
__global__ void __launch_bounds__(256) k3b_scan(char* ws) {
  unsigned* ctrl = (unsigned*)(ws + OFF_CTRL);
  unsigned* hist = (unsigned*)(ws + OFF_HIST);
  __shared__ unsigned ssum[256]; __shared__ int schunk; __shared__ unsigned scum;
  __shared__ unsigned sb[256];
  unsigned P = ctrl[0];
  int t = threadIdx.x;
  unsigned s = 0;
  for (int j = 0; j < 256; j++) s += hist[t * 256 + j];
  ssum[t] = s;
  __syncthreads();
  if (t == 0) {
    unsigned cum = 0; int c = 0;
    for (; c < 256; c++) { if (cum + ssum[c] >= P) break; cum += ssum[c]; }
    if (c == 256) c = 255;
    schunk = c; scum = cum;
  }
  __syncthreads();
  sb[t] = hist[schunk * 256 + t];
  __syncthreads();
  if (t == 0) {
    unsigned cum = scum; int j = 0;
    for (; j < 256; j++) { if (cum + sb[j] >= P) break; cum += sb[j]; }
    if (j == 256) j = 255;
    ctrl[4] = (unsigned)(schunk * 256 + j);
    ctrl[5] = cum;
    ctrl[6] = (P > cum) ? (P - cum) : 0u;
  }
}

// ---------------- K3c: gather cutoff-bin elements ----------------
__global__ void __launch_bounds__(256) k3c_ties(char* ws) {
  int i = blockIdx.x * 256 + threadIdx.x;
  unsigned* ctrl = (unsigned*)(ws + OFF_CTRL);
  const unsigned char* flags = (const unsigned char*)(ws + OFF_FLAGS);
  const uint32_t* uarr = (const uint32_t*)(ws + OFF_UARR);
  if (flags[i] & 2) {
    uint32_t v = uarr[i];
    if ((v >> 7) == ctrl[4]) {
      unsigned slot = atomicAdd(&ctrl[3], 1u);
      if (slot < MAXTIE) {
        unsigned* tie = (unsigned*)(ws + OFF_TIE);
        tie[2 * slot] = v; tie[2 * slot + 1] = (unsigned)i;
      }
    }
  }
}

// ---------------- K3d: exact lexicographic cutoff ----------------
__global__ void k3d_cut(char* ws) {
  unsigned* ctrl = (unsigned*)(ws + OFF_CTRL);
  unsigned* tie = (unsigned*)(ws + OFF_TIE);
  unsigned r = ctrl[6];
  unsigned ntie = ctrl[3]; if (ntie > MAXTIE) ntie = MAXTIE;
  unsigned ucut; int icut;
  if (r == 0) { ucut = ctrl[4] << 7; icut = -1; }
  else {
    if (r > ntie) r = ntie;
    unsigned curU = 0; int curI = -1;
    for (unsigned s = 0; s < r; s++) {
      unsigned bu = 0xFFFFFFFFu; int bi = 0x7FFFFFFF;
      for (unsigned j = 0; j < ntie; j++) {
        unsigned u = tie[2 * j]; int idx = (int)tie[2 * j + 1];
        bool gtcur = (u > curU) || (u == curU && idx > curI);
        bool ltbest = (u < bu) || (u == bu && idx < bi);
        if (gtcur && ltbest) { bu = u; bi = idx; }
      }
      curU = bu; curI = bi;
    }
    ucut = curU; icut = curI;
  }
  ctrl[7] = ucut; ctrl[8] = (unsigned)icut;
}

// ---------------- K3e: mark selected negatives ----------------
__global__ void __launch_bounds__(256) k3e_sel(char* ws) {
  int i = blockIdx.x * 256 + threadIdx.x;
  unsigned* ctrl = (unsigned*)(ws + OFF_CTRL);
  const unsigned char* flags = (const unsigned char*)(ws + OFF_FLAGS);
  const uint32_t* uarr = (const uint32_t*)(ws + OFF_UARR);
  if (flags[i] & 2) {
    uint32_t v = uarr[i];
    uint32_t ucut = ctrl[7]; int icut = (int)ctrl[8];
    if (v < ucut || (v == ucut && i <= icut)) {
      unsigned slot = atomicAdd(&ctrl[1], 1u);
      if (slot < MAXSEL) ((int*)(ws + OFF_SELL))[slot] = i;
    }
  }
}

// ---------------- K4a: mark needed pixels ----------------
__global__ void __launch_bounds__(256) k4a_mark(char* ws) {
  int j = blockIdx.x * 256 + threadIdx.x;   // [0, MAXPOS+MAXSEL)
  unsigned* ctrl = (unsigned*)(ws + OFF_CTRL);
  int np = min((int)ctrl[0], MAXPOS), ns = min((int)ctrl[1], MAXSEL);
  int i = -1;
  if (j < MAXPOS) { if (j < np) i = ((const int*)(ws + OFF_POSL))[j]; }
  else { int q = j - MAXPOS; if (q < ns) i = ((const int*)(ws + OFF_SELL))[q]; }
  if (i >= 0) {
    int b = i / M_; int m = i - b * M_; int pix = m / 42;
    ((unsigned char*)(ws + OFF_NEED))[b * 4096 + pix] = 1;
  }
}

// ---------------- K4b: assign pixel slots ----------------
__global__ void __launch_bounds__(256) k4b_slots(char* ws) {
  int pixg = blockIdx.x * 256 + threadIdx.x;   // [0, 32768)
  unsigned* ctrl = (unsigned*)(ws + OFF_CTRL);
  if (((const unsigned char*)(ws + OFF_NEED))[pixg]) {
    unsigned slot = atomicAdd(&ctrl[2], 1u);
    int* slotmap = (int*)(ws + OFF_SLOT);
    if (slot < MAXPIX) { slotmap[pixg] = (int)slot; ((int*)(ws + OFF_PLIST))[slot] = pixg; }
    else slotmap[pixg] = -1;
  }
}

// ---------------- K4c: im2col for needed pixels ----------------
__global__ void __launch_bounds__(256) k4c_im2col(const float* __restrict__ fm, char* ws) {
  unsigned* ctrl = (unsigned*)(ws + OFF_CTRL);
  int npix = min((int)ctrl[2], MAXPIX);
  int blk = blockIdx.x;
  if (blk >= npix) return;
  int pixg = ((const int*)(ws + OFF_PLIST))[blk];
  int b = pixg >> 12, pix = pixg & 4095;
  int y = pix >> 6, x = pix & 63;
  float* Ap = (float*)(ws + OFF_APATCH) + (size_t)blk * KK;
  for (int idx = threadIdx.x; idx < KK; idx += 256) {
    int ic = idx / 9, r = idx - ic * 9;
    int dy = r / 3, dx = r - dy * 3;
    int yy = y + dy - 1, xx = x + dx - 1;
    float v = 0.f;
    if (yy >= 0 && yy < 64 && xx >= 0 && xx < 64)
      v = fm[(((size_t)b * CIN + ic) * 64 + yy) * 64 + xx];
    Ap[idx] = v;
  }
}

// ---------------- K5: sparse conv1 GEMM (k-split, atomic accumulate) ----------------
constexpr int OCB = 32, KCB = 288;
constexpr int NKCH = KK / KCB;          // 8
constexpr int NOCH = HIDN / OCB;        // 16
constexpr int PXSTRIP = 64, NSTRIP = MAXPIX / PXSTRIP;  // 16
constexpr int PXT = 32;

__global__ void __launch_bounds__(256) k5_gemm(const float* __restrict__ w1, char* ws) {
  unsigned* ctrl = (unsigned*)(ws + OFF_CTRL);
  int npix = min((int)ctrl[2], MAXPIX);
  int bidx = blockIdx.x;
  int s = bidx / (NOCH * NKCH);
  int r = bidx - s * (NOCH * NKCH);
  int och = r % NOCH, kch = r / NOCH;
  int px0 = s * PXSTRIP;
  if (px0 >= npix) return;
  int oc0 = och * OCB, k0 = kch * KCB;
  const float* Ap = (const float*)(ws + OFF_APATCH);
  float* hid = (float*)(ws + OFF_HID);
  __shared__ float At[PXT][KCB + 4];
  int t = threadIdx.x;
  int oc_h = t & 15;       // oc = oc0+oc_h and oc0+oc_h+16
  int pj = t >> 4;         // px pair: 2*pj, 2*pj+1
  const float* Wg0 = w1 + (size_t)(oc0 + oc_h) * KK + k0;
  const float* Wg1 = Wg0 + (size_t)16 * KK;
  int pxEnd = min(px0 + PXSTRIP, npix);
  for (int pt = px0; pt < pxEnd; pt += PXT) {
    for (int idx = t; idx < PXT * KCB; idx += 256) {
      int j = idx / KCB, k = idx - j * KCB;
      int px = pt + j;
      At[j][k] = (px < npix) ? Ap[(size_t)px * KK + k0 + k] : 0.f;
    }
    __syncthreads();
    float a00 = 0.f, a01 = 0.f, a10 = 0.f, a11 = 0.f;
    int j0 = pj * 2, j1 = pj * 2 + 1;
    for (int k = 0; k < KCB; k += 4) {
      float4 w0 = *(const float4*)(Wg0 + k);
      float4 w1v = *(const float4*)(Wg1 + k);
      float4 x0 = *(const float4*)(&At[j0][k]);
      float4 x1 = *(const float4*)(&At[j1][k]);
      a00 += w0.x * x0.x + w0.y * x0.y + w0.z * x0.z + w0.w * x0.w;
      a01 += w0.x * x1.x + w0.y * x1.y + w0.z * x1.z + w0.w * x1.w;
      a10 += w1v.x * x0.x + w1v.y * x0.y + w1v.z * x0.z + w1v.w * x0.w;
      a11 += w1v.x * x1.x + w1v.y * x1.y + w1v.z * x1.z + w1v.w * x1.w;
    }
    int pa = pt + j0, pb = pt + j1;
    if (pa < npix) {
      atomicAdd(&hid[(size_t)pa * HIDN + oc0 + oc_h], a00);
      atomicAdd(&hid[(size_t)pa * HIDN + oc0 + oc_h + 16], a10);
    }
    if (pb < npix) {
      atomicAdd(&hid[(size_t)pb * HIDN + oc0 + oc_h], a01);
      atomicAdd(&hid[(size_t)pb * HIDN + oc0 + oc_h + 16], a11);
    }
    __syncthreads();
  }
}

// ---------------- K6: heads + loss accumulation ----------------
__global__ void __launch_bounds__(256) k6_head(const float* __restrict__ b1,
                                               const float* __restrict__ cw,
                                               const float* __restrict__ cb,
                                               const float* __restrict__ rw,
                                               const float* __restrict__ rb, char* ws) {
  unsigned* ctrl = (unsigned*)(ws + OFF_CTRL);
  float* accum = (float*)(ctrl + 16);
  int np = min((int)ctrl[0], MAXPOS);
  int ns = min((int)ctrl[1], MAXSEL);
  int nent = np + ns;
  const int* posl = (const int*)(ws + OFF_POSL);
  const int* sell = (const int*)(ws + OFF_SELL);
  const int* slotmap = (const int*)(ws + OFF_SLOT);
  const float* hid = (const float*)(ws + OFF_HID);
  const unsigned char* a2g = (const unsigned char*)(ws + OFF_A2G);
  const float* gs = (const float*)(ws + OFF_GSAFE);
  const float* basef = (const float*)(ws + OFF_BASE);
  int lane = threadIdx.x & 63;
  int gwave = blockIdx.x * 4 + (threadIdx.x >> 6);
  int nwaves = gridDim.x * 4;
  for (int e = gwave; e < nent; e += nwaves) {
    bool isPos = e < np;
    int i = isPos ? posl[e] : sell[e - np];
    int b = i / M_; int m = i - b * M_;
    int pix = m / 42; int a = m - pix * 42;
    int y = pix >> 6, x = pix & 63;
    int slot = slotmap[b * 4096 + pix];
    if (slot < 0 || slot >= MAXPIX) continue;
    float h[8];
    const float* hr = hid + (size_t)slot * HIDN;
#pragma unroll
    for (int j = 0; j < 8; j++) {
      int c = lane + j * 64;
      float v = hr[c] + b1[c];
      h[j] = v > 0.f ? v : 0.f;
    }
    const float* cwr = cw + (size_t)a * HIDN;
    float cp = 0.f;
#pragma unroll
    for (int j = 0; j < 8; j++) cp += h[j] * cwr[lane + j * 64];
#pragma unroll
    for (int off = 32; off >= 1; off >>= 1) cp += __shfl_xor(cp, off, 64);
    float conf = cp + cb[a];
    if (isPos) {
      float rp[4];
#pragma unroll
      for (int d = 0; d < 4; d++) {
        const float* rwr = rw + (size_t)(a * 4 + d) * HIDN;
        float sd = 0.f;
#pragma unroll
        for (int j = 0; j < 8; j++) sd += h[j] * rwr[lane + j * 64];
#pragma unroll
        for (int off = 32; off >= 1; off >>= 1) sd += __shfl_xor(sd, off, 64);
        rp[d] = sd + rb[a * 4 + d];
      }
      if (lane == 0) {
#pragma clang fp contract(off)
        float ay0, ax0, ay1, ax1, areaA;
        anchor_box(basef, a, y, x, ay0, ax0, ay1, ax1, areaA);
        int gidx = a2g[i];
        const float* g = gs + (size_t)(b * 20 + gidx) * 4;
        float acy = (ay0 + ay1) * 0.5f, acx = (ax0 + ax1) * 0.5f;
        float ah = ay1 - ay0, aw = ax1 - ax0;
        float gcy = (g[0] + g[2]) * 0.5f, gcx = (g[1] + g[3]) * 0.5f;
        float gh = g[2] - g[0], gw = g[3] - g[1];
        float t0 = (gcy - acy) / ah, t1 = (gcx - acx) / aw;
        float t2 = logf(gh / ah), t3 = logf(gw / aw);
        float sL = sl1(rp[0] - t0) + sl1(rp[1] - t1) + sl1(rp[2] - t2) + sl1(rp[3] - t3);
        atomicAdd(&accum[2], sL);
        atomicAdd(&accum[0], softplusf(-conf));
      }
    } else {
      if (lane == 0) atomicAdd(&accum[1], softplusf(conf));
    }
  }
}

// ---------------- K7: finalize ----------------
__global__ void k7_final(char* ws, float* out) {
  unsigned* ctrl = (unsigned*)(ws + OFF_CTRL);
  float* accum = (float*)(ctrl + 16);
  float P = (float)ctrl[0];
  float S = (float)ctrl[1];
  float cls = 0.5f * (accum[0] / P + accum[1] / S);
  float reg = accum[2] / (P * 4.0f);
  out[0] = cls + reg;
}

// ---------------- launcher ----------------
extern "C" void kernel_launch(void* const* d_in, const int* in_sizes, int n_in,
                              void* d_out, int out_size, void* d_ws, size_t ws_size,
                              hipStream_t stream) {
  const float* fm = (const float*)d_in[0];
  const float* gt = (const float*)d_in[1];
  const float* w1 = (const float*)d_in[3];
  const float* b1 = (const float*)d_in[4];
  const float* cw = (const float*)d_in[5];
  const float* cb = (const float*)d_in[6];
  const float* rw = (const float*)d_in[7];
  const float* rb = (const float*)d_in[8];
  char* ws = (char*)d_ws;
  float* out = (float*)d_out;

  hipMemsetAsync(ws, 0, ZERO_END, stream);
  hipMemsetAsync(ws + OFF_HID, 0, (size_t)MAXPIX * HIDN * 4, stream);

  k0_prep<<<1, 256, 0, stream>>>(gt, ws);
  k1_maxgt<<<NA / 256, 256, 0, stream>>>(ws);
  k2_assign<<<NA / 256, 256, 0, stream>>>(ws);
  k3a_scores<<<HALF / 256, 256, 0, stream>>>(ws);
  k3b_scan<<<1, 256, 0, stream>>>(ws);
  k3c_ties<<<NA / 256, 256, 0, stream>>>(ws);
  k3d_cut<<<1, 1, 0, stream>>>(ws);
  k3e_sel<<<NA / 256, 256, 0, stream>>>(ws);
  k4a_mark<<<(MAXPOS + MAXSEL) / 256, 256, 0, stream>>>(ws);
  k4b_slots<<<(B_ * 4096) / 256, 256, 0, stream>>>(ws);
  k4c_im2col<<<MAXPIX, 256, 0, stream>>>(fm, ws);
  k5_gemm<<<NSTRIP * NOCH * NKCH, 256, 0, stream>>>(w1, ws);
  k6_head<<<512, 256, 0, stream>>>(b1, cw, cb, rw, rb, ws);
  k7_final<<<1, 1, 0, stream>>>(ws, out);
}

// Round 2
// 286.265 us; speedup vs baseline: 1.8295x; 1.8295x over previous
//
#include <hip/hip_runtime.h>
#include <stdint.h>

// ---------------- problem constants ----------------
constexpr int B_  = 8, HM = 64, WM = 64, A_ = 42, CIN = 256, HIDN = 512;
constexpr int M_  = HM * WM * A_;          // 172032 anchors per image
constexpr int NA  = B_ * M_;               // 1376256 total anchors
constexpr int HALF = NA / 2;               // 688128 (threefry pairing)
constexpr int KK  = CIN * 9;               // 2304 (im2col K)
constexpr float NEG_T = 0.3f, POS_T = 0.5f;

// positives / per-GT max can only occur in this window:
// anchor y0 = 8 - h/2 + 16y must be < max GT coord 63.75; h<=160 -> y<=8; w<=113.14 -> x<=7.
constexpr int WINY = 10, WINX = 10, WPIX = WINY * WINX;   // safe margin
constexpr int PERIMG = A_ * WPIX;                         // 4200

constexpr int MAXPOS = 4096, MAXSEL = 4096, MAXCAND = 16384, MAXPIX = 1024, MAXTIE = 256;
constexpr uint32_t VCAND = 16384u;   // candidate threshold on 23-bit uniform; E[cand]=2688 >> P~120

// ---------------- workspace layout (bytes) ----------------
constexpr size_t OFF_CTRL  = 0;                       // u32[64]; accums f32 at [16..18]
constexpr size_t OFF_MAXGT = 256;                     // i32[160] (f32 bits)
constexpr size_t OFF_NEED  = 1024;                    // u8[32768]
constexpr size_t ZERO_END  = 1024 + 32768;            // memset [0, 33792)
constexpr size_t OFF_SLOT  = 33792;                   // i32[32768]
constexpr size_t OFF_PLIST = 33792 + 131072;          // i32[MAXPIX]        = 164864
constexpr size_t OFF_POSL  = 164864 + 4096;           // u32[MAXPOS] packed = 168960
constexpr size_t OFF_SELL  = 168960 + 16384;          // i32[MAXSEL]        = 185344
constexpr size_t OFF_CAND  = 185344 + 16384;          // uint2[MAXCAND]     = 201728
constexpr size_t OFF_HID   = 201728 + 131072;         // f32[MAXPIX*HIDN]   = 332800
constexpr size_t OFF_APATCH= 332800 + 2097152;        // f32[MAXPIX*KK]     = 2429952
// total ~11.9 MB

// ctrl: 0 nPos, 1 nSel, 2 nPix, 3 nCand, 10 k6 done-counter; f32 accums at ctrl[16..18]

// ---------------- helpers ----------------
__device__ __forceinline__ float iou_pair(float ay0, float ax0, float ay1, float ax1,
                                          float areaA, float g0, float g1, float g2, float g3,
                                          float areaG) {
#pragma clang fp contract(off)
  float ty = fmaxf(ay0, g0), tx = fmaxf(ax0, g1);
  float by = fminf(ay1, g2), bx = fminf(ax1, g3);
  float hy = by - ty; hy = fmaxf(hy, 0.f);
  float hx = bx - tx; hx = fmaxf(hx, 0.f);
  float inter = hy * hx;
  return inter / (areaA + areaG - inter);
}

__device__ __forceinline__ void anchor_box(const float* basef, int a, int y, int x,
                                           float& ay0, float& ax0, float& ay1, float& ax1,
                                           float& areaA) {
#pragma clang fp contract(off)
  double sy = 16.0 * (double)y, sx = 16.0 * (double)x;
  ay0 = (float)((double)basef[a * 4 + 0] + sy);
  ax0 = (float)((double)basef[a * 4 + 1] + sx);
  ay1 = (float)((double)basef[a * 4 + 2] + sy);
  ax1 = (float)((double)basef[a * 4 + 3] + sx);
  areaA = (ay1 - ay0) * (ax1 - ax0);
}

__device__ __forceinline__ void fill_base(float* sbase) {
  int t = threadIdx.x;
  if (t < 42) {
    const double SC[6] = {2.0, 2.5, 3.0, 3.5, 4.0, 5.0};
    const double RA[7] = {0.5, 1.5, 2.0, 2.5, 3.0, 3.5, 4.0};
    int si = t / 7, ri = t - si * 7;
    double h = 16.0 * SC[si] * sqrt(RA[ri]);
    double w = 16.0 * SC[si] * sqrt(1.0 / RA[ri]);
    sbase[t * 4 + 0] = (float)(8.0 - h / 2.0);
    sbase[t * 4 + 1] = (float)(8.0 - w / 2.0);
    sbase[t * 4 + 2] = (float)(8.0 + h / 2.0);
    sbase[t * 4 + 3] = (float)(8.0 + w / 2.0);
  }
}

// prep 20 GT rows of image b into LDS
__device__ __forceinline__ void fill_gt(const float* gt, int b, float* sg, float* sarea,
                                        unsigned* sval) {
  int t = threadIdx.x;
  if (t < 20) {
#pragma clang fp contract(off)
    float g4[4];
    for (int d = 0; d < 4; d++) {
      float v = gt[(b * 20 + t) * 4 + d];
      g4[d] = (v == -1.0f) ? -1.0f : v * 0.0625f;
    }
    unsigned valid = (g4[0] >= 0.0f) ? 1u : 0u;
    if (!valid) { g4[0] = 0.f; g4[1] = 0.f; g4[2] = 1.f; g4[3] = 1.f; }
    sg[t * 4 + 0] = g4[0]; sg[t * 4 + 1] = g4[1]; sg[t * 4 + 2] = g4[2]; sg[t * 4 + 3] = g4[3];
    sarea[t] = (g4[2] - g4[0]) * (g4[3] - g4[1]);
    sval[t] = valid;
  }
}

__device__ __forceinline__ float softplusf(float x) {
  return fmaxf(x, 0.f) + log1pf(expf(-fabsf(x)));
}
__device__ __forceinline__ float sl1(float d) {
  float ad = fabsf(d);
  return ad < 1.f ? 0.5f * ad * ad : ad - 0.5f;
}

__device__ __forceinline__ void tf_round(uint32_t& x0, uint32_t& x1, int r) {
  x0 += x1; x1 = (x1 << r) | (x1 >> (32 - r)); x1 ^= x0;
}
__device__ __forceinline__ void threefry(uint32_t c0, uint32_t c1, uint32_t& o0, uint32_t& o1) {
  const uint32_t k0 = 0u, k1 = 7u;
  const uint32_t k2 = k0 ^ k1 ^ 0x1BD11BDAu;
  uint32_t x0 = c0 + k0, x1 = c1 + k1;
  tf_round(x0, x1, 13); tf_round(x0, x1, 15); tf_round(x0, x1, 26); tf_round(x0, x1, 6);
  x0 += k1; x1 += k2 + 1u;
  tf_round(x0, x1, 17); tf_round(x0, x1, 29); tf_round(x0, x1, 16); tf_round(x0, x1, 24);
  x0 += k2; x1 += k0 + 2u;
  tf_round(x0, x1, 13); tf_round(x0, x1, 15); tf_round(x0, x1, 26); tf_round(x0, x1, 6);
  x0 += k0; x1 += k1 + 3u;
  tf_round(x0, x1, 17); tf_round(x0, x1, 29); tf_round(x0, x1, 16); tf_round(x0, x1, 24);
  x0 += k1; x1 += k2 + 4u;
  tf_round(x0, x1, 13); tf_round(x0, x1, 15); tf_round(x0, x1, 26); tf_round(x0, x1, 6);
  x0 += k2; x1 += k0 + 5u;
  o0 = x0; o1 = x1;
}

// ---------------- K1w: per-GT max IoU (windowed) ----------------
__global__ void __launch_bounds__(256) k1w(const float* __restrict__ gt, char* ws) {
  __shared__ float sbase[168], sg[80], sarea[20];
  __shared__ unsigned sval[20];
  __shared__ int smax[20];
  int b = blockIdx.y, t = threadIdx.x;
  fill_base(sbase);
  fill_gt(gt, b, sg, sarea, sval);
  if (t < 20) smax[t] = 0;
  __syncthreads();
  int idx = blockIdx.x * 256 + t;
  if (idx < PERIMG) {
    int a = idx / WPIX, p = idx - a * WPIX;
    int y = p / WINX, x = p - y * WINX;
    float ay0, ax0, ay1, ax1, areaA;
    anchor_box(sbase, a, y, x, ay0, ax0, ay1, ax1, areaA);
    for (int n = 0; n < 20; n++) {
      if (!sval[n]) continue;
      float io = iou_pair(ay0, ax0, ay1, ax1, areaA,
                          sg[n * 4], sg[n * 4 + 1], sg[n * 4 + 2], sg[n * 4 + 3], sarea[n]);
      if (io > 0.f) atomicMax(&smax[n], __float_as_int(io));
    }
  }
  __syncthreads();
  if (t < 20 && smax[t] != 0) atomicMax((int*)(ws + OFF_MAXGT) + b * 20 + t, smax[t]);
}

// ---------------- K2w: positives (windowed) ----------------
__global__ void __launch_bounds__(256) k2w(const float* __restrict__ gt, char* ws) {
  __shared__ float sbase[168], sg[80], sarea[20], smg[20];
  __shared__ unsigned sval[20];
  int b = blockIdx.y, t = threadIdx.x;
  fill_base(sbase);
  fill_gt(gt, b, sg, sarea, sval);
  if (t < 20) smg[t] = __int_as_float(((int*)(ws + OFF_MAXGT))[b * 20 + t]);
  __syncthreads();
  int idx = blockIdx.x * 256 + t;
  if (idx >= PERIMG) return;
  int a = idx / WPIX, p = idx - a * WPIX;
  int y = p / WINX, x = p - y * WINX;
  float ay0, ax0, ay1, ax1, areaA;
  anchor_box(sbase, a, y, x, ay0, ax0, ay1, ax1, areaA);
  float best = -1.f; int arg = 0; bool pos = false;
  for (int n = 0; n < 20; n++) {
    float io = 0.f;
    if (sval[n]) io = iou_pair(ay0, ax0, ay1, ax1, areaA,
                               sg[n * 4], sg[n * 4 + 1], sg[n * 4 + 2], sg[n * 4 + 3], sarea[n]);
    if (io > best) { best = io; arg = n; }
    float mg = smg[n];
    pos = pos || ((io == mg) && (mg > 0.f)) || (io > POS_T);
  }
  if (pos) {
    int pix = y * 64 + x;
    int i = b * M_ + pix * 42 + a;
    unsigned slot = atomicAdd((unsigned*)(ws + OFF_CTRL) + 0, 1u);
    if (slot < MAXPOS) ((unsigned*)(ws + OFF_POSL))[slot] = (unsigned)i | ((unsigned)arg << 21);
    ((unsigned char*)(ws + OFF_NEED))[b * 4096 + pix] = 1;
  }
}

// ---------------- K3a: threefry -> small-value candidates (+zero HID) ----------------
__global__ void __launch_bounds__(256) k3a(char* ws) {
  int p = blockIdx.x * 256 + threadIdx.x;    // [0, HALF)
  float* hid = (float*)(ws + OFF_HID);
  if (p < MAXPIX * HIDN) hid[p] = 0.f;       // fold HID zeroing here
  uint32_t o0, o1; threefry((uint32_t)p, (uint32_t)(p + HALF), o0, o1);
  uint32_t v0 = o0 >> 9, v1 = o1 >> 9;
  unsigned* ctrl = (unsigned*)(ws + OFF_CTRL);
  uint2* cand = (uint2*)(ws + OFF_CAND);
  if (v0 < VCAND) {
    unsigned s = atomicAdd(&ctrl[3], 1u);
    if (s < MAXCAND) cand[s] = make_uint2(v0, (unsigned)p);
  }
  if (v1 < VCAND) {
    unsigned s = atomicAdd(&ctrl[3], 1u);
    if (s < MAXCAND) cand[s] = make_uint2(v1, (unsigned)(p + HALF));
  }
}

// ---------------- K3sel: exact P-smallest selection on candidate list ----------------
__global__ void __launch_bounds__(256) k3sel(char* ws) {
  __shared__ unsigned bins[128];
  __shared__ uint2 ties[MAXTIE];
  __shared__ unsigned tcnt, s_r, s_ucut;
  __shared__ int s_icut, s_cutbin;
  unsigned* ctrl = (unsigned*)(ws + OFF_CTRL);
  const uint2* cand = (const uint2*)(ws + OFF_CAND);
  int t = threadIdx.x;
  unsigned P = min(ctrl[0], (unsigned)MAXPOS);
  unsigned nc = min(ctrl[3], (unsigned)MAXCAND);
  if (t < 128) bins[t] = 0;
  if (t == 0) tcnt = 0;
  __syncthreads();
  for (unsigned j = t; j < nc; j += 256) atomicAdd(&bins[cand[j].x >> 7], 1u);
  __syncthreads();
  if (t == 0) {
    unsigned cum = 0; int c = 0;
    for (; c < 128; c++) { if (cum + bins[c] >= P) break; cum += bins[c]; }
    if (c == 128) c = 127;
    s_cutbin = c; s_r = (P > cum) ? (P - cum) : 0u;
  }
  __syncthreads();
  int cutbin = s_cutbin;
  for (unsigned j = t; j < nc; j += 256)
    if ((int)(cand[j].x >> 7) == cutbin) {
      unsigned k = atomicAdd(&tcnt, 1u);
      if (k < MAXTIE) ties[k] = cand[j];
    }
  __syncthreads();
  if (t == 0) {
    unsigned n = min(tcnt, (unsigned)MAXTIE);
    unsigned r = s_r; if (r > n) r = n;
    unsigned curV = 0; int curI = -1;
    for (unsigned s = 0; s < r; s++) {
      unsigned bu = 0xFFFFFFFFu; int bi = 0x7FFFFFFF;
      for (unsigned j = 0; j < n; j++) {
        unsigned u = ties[j].x; int idx = (int)ties[j].y;
        bool gtcur = (u > curV) || (u == curV && idx > curI);
        bool ltbest = (u < bu) || (u == bu && idx < bi);
        if (gtcur && ltbest) { bu = u; bi = idx; }
      }
      curV = bu; curI = bi;
    }
    if (r == 0) { curV = 0; curI = -1; }   // selects nothing (P==0 can't happen)
    s_ucut = curV; s_icut = curI;
  }
  __syncthreads();
  unsigned ucut = s_ucut; int icut = s_icut;
  unsigned char* need = (unsigned char*)(ws + OFF_NEED);
  for (unsigned j = t; j < nc; j += 256) {
    unsigned v = cand[j].x; int i = (int)cand[j].y;
    if (v < ucut || (v == ucut && i <= icut)) {
      unsigned slot = atomicAdd(&ctrl[1], 1u);
      if (slot < MAXSEL) {
        ((int*)(ws + OFF_SELL))[slot] = i;
        int b = i / M_; int m = i - b * M_;
        need[b * 4096 + m / 42] = 1;
      }
    }
  }
}

// ---------------- K4b: assign pixel slots ----------------
__global__ void __launch_bounds__(256) k4b_slots(char* ws) {
  int pixg = blockIdx.x * 256 + threadIdx.x;   // [0, 32768)
  unsigned* ctrl = (unsigned*)(ws + OFF_CTRL);
  if (((const unsigned char*)(ws + OFF_NEED))[pixg]) {
    unsigned slot = atomicAdd(&ctrl[2], 1u);
    int* slotmap = (int*)(ws + OFF_SLOT);
    if (slot < MAXPIX) { slotmap[pixg] = (int)slot; ((int*)(ws + OFF_PLIST))[slot] = pixg; }
    else slotmap[pixg] = -1;
  }
}

// ---------------- K4c: im2col for needed pixels ----------------
__global__ void __launch_bounds__(256) k4c_im2col(const float* __restrict__ fm, char* ws) {
  unsigned* ctrl = (unsigned*)(ws + OFF_CTRL);
  int npix = min((int)ctrl[2], MAXPIX);
  int blk = blockIdx.x;
  if (blk >= npix) return;
  int pixg = ((const int*)(ws + OFF_PLIST))[blk];
  int b = pixg >> 12, pix = pixg & 4095;
  int y = pix >> 6, x = pix & 63;
  float* Ap = (float*)(ws + OFF_APATCH) + (size_t)blk * KK;
  for (int idx = threadIdx.x; idx < KK; idx += 256) {
    int ic = idx / 9, r = idx - ic * 9;
    int dy = r / 3, dx = r - dy * 3;
    int yy = y + dy - 1, xx = x + dx - 1;
    float v = 0.f;
    if (yy >= 0 && yy < 64 && xx >= 0 && xx < 64)
      v = fm[(((size_t)b * CIN + ic) * 64 + yy) * 64 + xx];
    Ap[idx] = v;
  }
}

// ---------------- K5: sparse conv1 tiled GEMM ----------------
// tile 64px x 64oc, K-split 16 (KCH=144), kstep 16, double-buffered LDS.
constexpr int KSPL = 16, KCH = KK / KSPL;    // 144
constexpr int NST = KCH / 16;                // 9 stages

__global__ void __launch_bounds__(256) k5_gemm(const float* __restrict__ w1, char* ws) {
  unsigned* ctrl = (unsigned*)(ws + OFF_CTRL);
  int npix = min((int)ctrl[2], MAXPIX);
  int bid = blockIdx.x;
  int strip = bid & 15, r2 = bid >> 4;
  int och = r2 & 7, ks = r2 >> 3;
  int px0 = strip * 64;
  if (px0 >= npix) return;
  int oc0 = och * 64, kb = ks * KCH;
  __shared__ float As[2][16][64];
  __shared__ float Wsm[2][16][64];
  const float* Ap = (const float*)(ws + OFF_APATCH);
  float* hid = (float*)(ws + OFF_HID);
  int t = threadIdx.x;
  int ls = t & 63, kc = t >> 6;         // staging mapping
  int tx = t & 15, ty = t >> 4;         // compute mapping: px=tx*4.., oc=2ty,2ty+1,2ty+32,2ty+33
  bool pxok = (px0 + ls) < npix;
  const float* Ag = Ap + (size_t)(px0 + ls) * KK + kb + kc * 4;
  const float* Wg = w1 + (size_t)(oc0 + ls) * KK + kb + kc * 4;
  float4 av = pxok ? *(const float4*)Ag : float4{0.f, 0.f, 0.f, 0.f};
  float4 wv = *(const float4*)Wg;
  As[0][kc * 4 + 0][ls] = av.x; As[0][kc * 4 + 1][ls] = av.y;
  As[0][kc * 4 + 2][ls] = av.z; As[0][kc * 4 + 3][ls] = av.w;
  Wsm[0][kc * 4 + 0][ls] = wv.x; Wsm[0][kc * 4 + 1][ls] = wv.y;
  Wsm[0][kc * 4 + 2][ls] = wv.z; Wsm[0][kc * 4 + 3][ls] = wv.w;
  float acc[4][4] = {};
  __syncthreads();
  for (int s = 0; s < NST; s++) {
    int cur = s & 1;
    float4 an = {0.f, 0.f, 0.f, 0.f}, wn = {0.f, 0.f, 0.f, 0.f};
    bool more = (s + 1 < NST);
    if (more) {
      if (pxok) an = *(const float4*)(Ag + (s + 1) * 16);
      wn = *(const float4*)(Wg + (s + 1) * 16);
    }
#pragma unroll
    for (int k = 0; k < 16; k++) {
      float4 a4 = *(const float4*)&As[cur][k][tx * 4];
      float2 w01 = *(const float2*)&Wsm[cur][k][2 * ty];
      float2 w23 = *(const float2*)&Wsm[cur][k][2 * ty + 32];
      acc[0][0] += w01.x * a4.x; acc[0][1] += w01.x * a4.y;
      acc[0][2] += w01.x * a4.z; acc[0][3] += w01.x * a4.w;
      acc[1][0] += w01.y * a4.x; acc[1][1] += w01.y * a4.y;
      acc[1][2] += w01.y * a4.z; acc[1][3] += w01.y * a4.w;
      acc[2][0] += w23.x * a4.x; acc[2][1] += w23.x * a4.y;
      acc[2][2] += w23.x * a4.z; acc[2][3] += w23.x * a4.w;
      acc[3][0] += w23.y * a4.x; acc[3][1] += w23.y * a4.y;
      acc[3][2] += w23.y * a4.z; acc[3][3] += w23.y * a4.w;
    }
    if (more) {
      int nxt = cur ^ 1;
      As[nxt][kc * 4 + 0][ls] = an.x; As[nxt][kc * 4 + 1][ls] = an.y;
      As[nxt][kc * 4 + 2][ls] = an.z; As[nxt][kc * 4 + 3][ls] = an.w;
      Wsm[nxt][kc * 4 + 0][ls] = wn.x; Wsm[nxt][kc * 4 + 1][ls] = wn.y;
      Wsm[nxt][kc * 4 + 2][ls] = wn.z; Wsm[nxt][kc * 4 + 3][ls] = wn.w;
    }
    __syncthreads();
  }
#pragma unroll
  for (int jj = 0; jj < 4; jj++) {
    int oc = oc0 + 2 * ty + (jj & 1) + 32 * (jj >> 1);
#pragma unroll
    for (int j = 0; j < 4; j++) {
      int px = px0 + tx * 4 + j;
      if (px < npix) atomicAdd(&hid[(size_t)px * HIDN + oc], acc[jj][j]);
    }
  }
}

// ---------------- K6: heads + loss + finalize ----------------
__global__ void __launch_bounds__(256) k6_head(const float* __restrict__ gt,
                                               const float* __restrict__ b1,
                                               const float* __restrict__ cw,
                                               const float* __restrict__ cb,
                                               const float* __restrict__ rw,
                                               const float* __restrict__ rb,
                                               char* ws, float* out) {
  __shared__ float sbase[168], sg[640];
  int t = threadIdx.x;
  fill_base(sbase);
  if (t < 160) {
#pragma clang fp contract(off)
    float g4[4];
    for (int d = 0; d < 4; d++) {
      float v = gt[t * 4 + d];
      g4[d] = (v == -1.0f) ? -1.0f : v * 0.0625f;
    }
    if (!(g4[0] >= 0.0f)) { g4[0] = 0.f; g4[1] = 0.f; g4[2] = 1.f; g4[3] = 1.f; }
    sg[t * 4 + 0] = g4[0]; sg[t * 4 + 1] = g4[1]; sg[t * 4 + 2] = g4[2]; sg[t * 4 + 3] = g4[3];
  }
  __syncthreads();
  unsigned* ctrl = (unsigned*)(ws + OFF_CTRL);
  float* accum = (float*)(ctrl + 16);
  int np = min((int)ctrl[0], MAXPOS);
  int ns = min((int)ctrl[1], MAXSEL);
  int nent = np + ns;
  const unsigned* posl = (const unsigned*)(ws + OFF_POSL);
  const int* sell = (const int*)(ws + OFF_SELL);
  const int* slotmap = (const int*)(ws + OFF_SLOT);
  const float* hid = (const float*)(ws + OFF_HID);
  int lane = t & 63;
  int gwave = blockIdx.x * 4 + (t >> 6);
  int nwaves = gridDim.x * 4;
  for (int e = gwave; e < nent; e += nwaves) {
    bool isPos = e < np;
    int i, arg = 0;
    if (isPos) { unsigned pck = posl[e]; i = (int)(pck & 0x1FFFFFu); arg = (int)(pck >> 21); }
    else i = sell[e - np];
    int b = i / M_; int m = i - b * M_;
    int pix = m / 42; int a = m - pix * 42;
    int y = pix >> 6, x = pix & 63;
    int slot = slotmap[b * 4096 + pix];
    if (slot < 0 || slot >= MAXPIX) continue;
    float h[8];
    const float* hr = hid + (size_t)slot * HIDN;
#pragma unroll
    for (int j = 0; j < 8; j++) {
      int c = lane + j * 64;
      float v = hr[c] + b1[c];
      h[j] = v > 0.f ? v : 0.f;
    }
    const float* cwr = cw + (size_t)a * HIDN;
    float cp = 0.f;
#pragma unroll
    for (int j = 0; j < 8; j++) cp += h[j] * cwr[lane + j * 64];
#pragma unroll
    for (int off = 32; off >= 1; off >>= 1) cp += __shfl_xor(cp, off, 64);
    float conf = cp + cb[a];
    if (isPos) {
      float rp[4];
#pragma unroll
      for (int d = 0; d < 4; d++) {
        const float* rwr = rw + (size_t)(a * 4 + d) * HIDN;
        float sd = 0.f;
#pragma unroll
        for (int j = 0; j < 8; j++) sd += h[j] * rwr[lane + j * 64];
#pragma unroll
        for (int off = 32; off >= 1; off >>= 1) sd += __shfl_xor(sd, off, 64);
        rp[d] = sd + rb[a * 4 + d];
      }
      if (lane == 0) {
#pragma clang fp contract(off)
        float ay0, ax0, ay1, ax1, areaA;
        anchor_box(sbase, a, y, x, ay0, ax0, ay1, ax1, areaA);
        const float* g = sg + (size_t)(b * 20 + arg) * 4;
        float acy = (ay0 + ay1) * 0.5f, acx = (ax0 + ax1) * 0.5f;
        float ah = ay1 - ay0, aw = ax1 - ax0;
        float gcy = (g[0] + g[2]) * 0.5f, gcx = (g[1] + g[3]) * 0.5f;
        float gh = g[2] - g[0], gw = g[3] - g[1];
        float t0 = (gcy - acy) / ah, t1 = (gcx - acx) / aw;
        float t2 = logf(gh / ah), t3 = logf(gw / aw);
        float sL = sl1(rp[0] - t0) + sl1(rp[1] - t1) + sl1(rp[2] - t2) + sl1(rp[3] - t3);
        atomicAdd(&accum[2], sL);
        atomicAdd(&accum[0], softplusf(-conf));
      }
    } else {
      if (lane == 0) atomicAdd(&accum[1], softplusf(conf));
    }
  }
  // finalize: last block writes the scalar output
  __syncthreads();
  if (t == 0) {
    __threadfence();
    unsigned done = atomicAdd(&ctrl[10], 1u);
    if (done == gridDim.x - 1) {
      __threadfence();
      float P = (float)min((int)ctrl[0], MAXPOS);
      float S = (float)min((int)ctrl[1], MAXSEL);
      float cls = 0.5f * (accum[0] / P + accum[1] / S);
      out[0] = cls + accum[2] / (P * 4.0f);
    }
  }
}

// ---------------- launcher ----------------
extern "C" void kernel_launch(void* const* d_in, const int* in_sizes, int n_in,
                              void* d_out, int out_size, void* d_ws, size_t ws_size,
                              hipStream_t stream) {
  const float* fm = (const float*)d_in[0];
  const float* gt = (const float*)d_in[1];
  const float* w1 = (const float*)d_in[3];
  const float* b1 = (const float*)d_in[4];
  const float* cw = (const float*)d_in[5];
  const float* cb = (const float*)d_in[6];
  const float* rw = (const float*)d_in[7];
  const float* rb = (const float*)d_in[8];
  char* ws = (char*)d_ws;
  float* out = (float*)d_out;

  hipMemsetAsync(ws, 0, ZERO_END, stream);

  dim3 wgrid((PERIMG + 255) / 256, B_);
  k1w<<<wgrid, 256, 0, stream>>>(gt, ws);
  k2w<<<wgrid, 256, 0, stream>>>(gt, ws);
  k3a<<<HALF / 256, 256, 0, stream>>>(ws);
  k3sel<<<1, 256, 0, stream>>>(ws);
  k4b_slots<<<(B_ * 4096) / 256, 256, 0, stream>>>(ws);
  k4c_im2col<<<MAXPIX, 256, 0, stream>>>(fm, ws);
  k5_gemm<<<8 * 16 * KSPL, 256, 0, stream>>>(w1, ws);
  k6_head<<<128, 256, 0, stream>>>(gt, b1, cw, cb, rw, rb, ws, out);
}

// Round 3
// 282.118 us; speedup vs baseline: 1.8563x; 1.0147x over previous
//
#include <hip/hip_runtime.h>
#include <stdint.h>

// ---------------- problem constants ----------------
constexpr int B_  = 8, HM = 64, WM = 64, A_ = 42, CIN = 256, HIDN = 512;
constexpr int M_  = HM * WM * A_;          // 172032 anchors per image
constexpr int NA  = B_ * M_;               // 1376256 total anchors
constexpr int HALF = NA / 2;               // 688128 (threefry pairing)
constexpr int KK  = CIN * 9;               // 2304 (im2col K)
constexpr float NEG_T = 0.3f, POS_T = 0.5f;

// positives / per-GT max can only occur in this window (anchors are in PIXEL
// units, GT in feature units <=63.75: overlap forces y<=8, x<=7; margin to 10)
constexpr int WINY = 10, WINX = 10, WPIX = WINY * WINX;
constexpr int PERIMG = A_ * WPIX;                         // 4200
constexpr int K1BLK = (PERIMG + 255) / 256;               // 17
constexpr int NK1 = K1BLK * B_;                           // 136

constexpr int MAXPOS = 4096, MAXSEL = 4096, MAXCAND = 16384, MAXPIX = 1024, MAXTIE = 256;
constexpr uint32_t VCAND = 16384u;   // candidate cut on 23-bit uniform; E[cand]=2688 >> P

// ---------------- workspace layout (bytes) ----------------
constexpr size_t OFF_CTRL  = 0;                       // u32[64]; f32 accums at [16..18]
constexpr size_t OFF_MAXGT = 256;                     // i32[160] (f32 bits)
constexpr size_t OFF_NEED  = 1024;                    // u8[32768]
constexpr size_t ZERO_END  = 1024 + 32768;            // memset [0, 33792)
constexpr size_t OFF_SLOT  = 33792;                   // i32[32768]
constexpr size_t OFF_PLIST = 33792 + 131072;          // i32[MAXPIX]
constexpr size_t OFF_POSL  = 164864 + 4096;           // u32[MAXPOS] packed
constexpr size_t OFF_SELL  = 168960 + 16384;          // i32[MAXSEL]
constexpr size_t OFF_CAND  = 185344 + 16384;          // uint2[MAXCAND]
constexpr size_t OFF_HID   = 201728 + 131072;         // f32[MAXPIX*HIDN] post bias+relu
constexpr size_t OFF_PART  = OFF_HID + (size_t)MAXPIX * HIDN * 4;   // f32[4][MAXPIX][HIDN]
constexpr size_t OFF_APATCH= OFF_PART + (size_t)4 * MAXPIX * HIDN * 4; // f32[MAXPIX*KK]
// total ~19.3 MB

// ctrl: 0 nPos, 1 nSel, 2 nPix, 3 nCand, 10 k6 done-counter; f32 accums ctrl[16..18]

// ---------------- helpers ----------------
__device__ __forceinline__ float iou_pair(float ay0, float ax0, float ay1, float ax1,
                                          float areaA, float g0, float g1, float g2, float g3,
                                          float areaG) {
#pragma clang fp contract(off)
  float ty = fmaxf(ay0, g0), tx = fmaxf(ax0, g1);
  float by = fminf(ay1, g2), bx = fminf(ax1, g3);
  float hy = by - ty; hy = fmaxf(hy, 0.f);
  float hx = bx - tx; hx = fmaxf(hx, 0.f);
  float inter = hy * hx;
  return inter / (areaA + areaG - inter);
}

__device__ __forceinline__ void anchor_box(const float* basef, int a, int y, int x,
                                           float& ay0, float& ax0, float& ay1, float& ax1,
                                           float& areaA) {
#pragma clang fp contract(off)
  double sy = 16.0 * (double)y, sx = 16.0 * (double)x;
  ay0 = (float)((double)basef[a * 4 + 0] + sy);
  ax0 = (float)((double)basef[a * 4 + 1] + sx);
  ay1 = (float)((double)basef[a * 4 + 2] + sy);
  ax1 = (float)((double)basef[a * 4 + 3] + sx);
  areaA = (ay1 - ay0) * (ax1 - ax0);
}

__device__ __forceinline__ void fill_base(float* sbase) {
  int t = threadIdx.x;
  if (t < 42) {
    const double SC[6] = {2.0, 2.5, 3.0, 3.5, 4.0, 5.0};
    const double RA[7] = {0.5, 1.5, 2.0, 2.5, 3.0, 3.5, 4.0};
    int si = t / 7, ri = t - si * 7;
    double h = 16.0 * SC[si] * sqrt(RA[ri]);
    double w = 16.0 * SC[si] * sqrt(1.0 / RA[ri]);
    sbase[t * 4 + 0] = (float)(8.0 - h / 2.0);
    sbase[t * 4 + 1] = (float)(8.0 - w / 2.0);
    sbase[t * 4 + 2] = (float)(8.0 + h / 2.0);
    sbase[t * 4 + 3] = (float)(8.0 + w / 2.0);
  }
}

__device__ __forceinline__ void fill_gt(const float* gt, int b, float* sg, float* sarea,
                                        unsigned* sval) {
  int t = threadIdx.x;
  if (t < 20) {
#pragma clang fp contract(off)
    float g4[4];
    for (int d = 0; d < 4; d++) {
      float v = gt[(b * 20 + t) * 4 + d];
      g4[d] = (v == -1.0f) ? -1.0f : v * 0.0625f;
    }
    unsigned valid = (g4[0] >= 0.0f) ? 1u : 0u;
    if (!valid) { g4[0] = 0.f; g4[1] = 0.f; g4[2] = 1.f; g4[3] = 1.f; }
    sg[t * 4 + 0] = g4[0]; sg[t * 4 + 1] = g4[1]; sg[t * 4 + 2] = g4[2]; sg[t * 4 + 3] = g4[3];
    sarea[t] = (g4[2] - g4[0]) * (g4[3] - g4[1]);
    sval[t] = valid;
  }
}

__device__ __forceinline__ float softplusf(float x) {
  return fmaxf(x, 0.f) + log1pf(expf(-fabsf(x)));
}
__device__ __forceinline__ float sl1(float d) {
  float ad = fabsf(d);
  return ad < 1.f ? 0.5f * ad * ad : ad - 0.5f;
}

__device__ __forceinline__ void tf_round(uint32_t& x0, uint32_t& x1, int r) {
  x0 += x1; x1 = (x1 << r) | (x1 >> (32 - r)); x1 ^= x0;
}
__device__ __forceinline__ void threefry(uint32_t c0, uint32_t c1, uint32_t& o0, uint32_t& o1) {
  const uint32_t k0 = 0u, k1 = 7u;
  const uint32_t k2 = k0 ^ k1 ^ 0x1BD11BDAu;
  uint32_t x0 = c0 + k0, x1 = c1 + k1;
  tf_round(x0, x1, 13); tf_round(x0, x1, 15); tf_round(x0, x1, 26); tf_round(x0, x1, 6);
  x0 += k1; x1 += k2 + 1u;
  tf_round(x0, x1, 17); tf_round(x0, x1, 29); tf_round(x0, x1, 16); tf_round(x0, x1, 24);
  x0 += k2; x1 += k0 + 2u;
  tf_round(x0, x1, 13); tf_round(x0, x1, 15); tf_round(x0, x1, 26); tf_round(x0, x1, 6);
  x0 += k0; x1 += k1 + 3u;
  tf_round(x0, x1, 17); tf_round(x0, x1, 29); tf_round(x0, x1, 16); tf_round(x0, x1, 24);
  x0 += k1; x1 += k2 + 4u;
  tf_round(x0, x1, 13); tf_round(x0, x1, 15); tf_round(x0, x1, 26); tf_round(x0, x1, 6);
  x0 += k2; x1 += k0 + 5u;
  o0 = x0; o1 = x1;
}

// ---------------- KA: threefry candidates + windowed per-GT max IoU ----------------
__global__ void __launch_bounds__(256) kA(const float* __restrict__ gt, char* ws) {
  __shared__ float sbase[168], sg[80], sarea[20];
  __shared__ unsigned sval[20];
  __shared__ int smax[20];
  int t = threadIdx.x;
  // --- threefry part (all 2688 blocks) ---
  int p = blockIdx.x * 256 + t;   // [0, HALF)
  uint32_t o0, o1; threefry((uint32_t)p, (uint32_t)(p + HALF), o0, o1);
  uint32_t v0 = o0 >> 9, v1 = o1 >> 9;
  unsigned* ctrl = (unsigned*)(ws + OFF_CTRL);
  uint2* cand = (uint2*)(ws + OFF_CAND);
  if (v0 < VCAND) {
    unsigned s = atomicAdd(&ctrl[3], 1u);
    if (s < MAXCAND) cand[s] = make_uint2(v0, (unsigned)p);
  }
  if (v1 < VCAND) {
    unsigned s = atomicAdd(&ctrl[3], 1u);
    if (s < MAXCAND) cand[s] = make_uint2(v1, (unsigned)(p + HALF));
  }
  // --- windowed per-GT max IoU (blocks < NK1) ---
  if (blockIdx.x < NK1) {
    int b = blockIdx.x / K1BLK, blk = blockIdx.x - b * K1BLK;
    fill_base(sbase);
    fill_gt(gt, b, sg, sarea, sval);
    if (t < 20) smax[t] = 0;
    __syncthreads();
    int idx = blk * 256 + t;
    if (idx < PERIMG) {
      int a = idx / WPIX, pp = idx - a * WPIX;
      int y = pp / WINX, x = pp - y * WINX;
      float ay0, ax0, ay1, ax1, areaA;
      anchor_box(sbase, a, y, x, ay0, ax0, ay1, ax1, areaA);
      for (int n = 0; n < 20; n++) {
        if (!sval[n]) continue;
        float io = iou_pair(ay0, ax0, ay1, ax1, areaA,
                            sg[n * 4], sg[n * 4 + 1], sg[n * 4 + 2], sg[n * 4 + 3], sarea[n]);
        if (io > 0.f) atomicMax(&smax[n], __float_as_int(io));
      }
    }
    __syncthreads();
    if (t < 20 && smax[t] != 0) atomicMax((int*)(ws + OFF_MAXGT) + b * 20 + t, smax[t]);
  }
}

// ---------------- K2w: positives (windowed) ----------------
__global__ void __launch_bounds__(256) k2w(const float* __restrict__ gt, char* ws) {
  __shared__ float sbase[168], sg[80], sarea[20], smg[20];
  __shared__ unsigned sval[20];
  int b = blockIdx.y, t = threadIdx.x;
  fill_base(sbase);
  fill_gt(gt, b, sg, sarea, sval);
  if (t < 20) smg[t] = __int_as_float(((int*)(ws + OFF_MAXGT))[b * 20 + t]);
  __syncthreads();
  int idx = blockIdx.x * 256 + t;
  if (idx >= PERIMG) return;
  int a = idx / WPIX, p = idx - a * WPIX;
  int y = p / WINX, x = p - y * WINX;
  float ay0, ax0, ay1, ax1, areaA;
  anchor_box(sbase, a, y, x, ay0, ax0, ay1, ax1, areaA);
  float best = -1.f; int arg = 0; bool pos = false;
  for (int n = 0; n < 20; n++) {
    float io = 0.f;
    if (sval[n]) io = iou_pair(ay0, ax0, ay1, ax1, areaA,
                               sg[n * 4], sg[n * 4 + 1], sg[n * 4 + 2], sg[n * 4 + 3], sarea[n]);
    if (io > best) { best = io; arg = n; }
    float mg = smg[n];
    pos = pos || ((io == mg) && (mg > 0.f)) || (io > POS_T);
  }
  if (pos) {
    int pix = y * 64 + x;
    int i = b * M_ + pix * 42 + a;
    unsigned slot = atomicAdd((unsigned*)(ws + OFF_CTRL) + 0, 1u);
    if (slot < MAXPOS) ((unsigned*)(ws + OFF_POSL))[slot] = (unsigned)i | ((unsigned)arg << 21);
    ((unsigned char*)(ws + OFF_NEED))[b * 4096 + pix] = 1;
  }
}

// ---------------- KSel: exact P-smallest selection + pixel slot assignment ----------------
__global__ void __launch_bounds__(256) kSel(char* ws) {
  __shared__ unsigned bins[128];
  __shared__ uint2 ties[MAXTIE];
  __shared__ unsigned tcnt, s_r, s_ucut, s_np;
  __shared__ int s_icut, s_cutbin;
  unsigned* ctrl = (unsigned*)(ws + OFF_CTRL);
  const uint2* cand = (const uint2*)(ws + OFF_CAND);
  int t = threadIdx.x;
  unsigned P = min(ctrl[0], (unsigned)MAXPOS);
  unsigned nc = min(ctrl[3], (unsigned)MAXCAND);
  if (t < 128) bins[t] = 0;
  if (t == 0) { tcnt = 0; s_np = 0; }
  __syncthreads();
  for (unsigned j = t; j < nc; j += 256) atomicAdd(&bins[cand[j].x >> 7], 1u);
  __syncthreads();
  if (t == 0) {
    unsigned cum = 0; int c = 0;
    for (; c < 128; c++) { if (cum + bins[c] >= P) break; cum += bins[c]; }
    if (c == 128) c = 127;
    s_cutbin = c; s_r = (P > cum) ? (P - cum) : 0u;
  }
  __syncthreads();
  int cutbin = s_cutbin;
  for (unsigned j = t; j < nc; j += 256)
    if ((int)(cand[j].x >> 7) == cutbin) {
      unsigned k = atomicAdd(&tcnt, 1u);
      if (k < MAXTIE) ties[k] = cand[j];
    }
  __syncthreads();
  if (t == 0) {
    unsigned n = min(tcnt, (unsigned)MAXTIE);
    unsigned r = s_r; if (r > n) r = n;
    unsigned curV = 0; int curI = -1;
    for (unsigned s = 0; s < r; s++) {
      unsigned bu = 0xFFFFFFFFu; int bi = 0x7FFFFFFF;
      for (unsigned j = 0; j < n; j++) {
        unsigned u = ties[j].x; int idx = (int)ties[j].y;
        bool gtcur = (u > curV) || (u == curV && idx > curI);
        bool ltbest = (u < bu) || (u == bu && idx < bi);
        if (gtcur && ltbest) { bu = u; bi = idx; }
      }
      curV = bu; curI = bi;
    }
    if (r == 0) { curV = 0; curI = -1; }
    s_ucut = curV; s_icut = curI;
  }
  __syncthreads();
  unsigned ucut = s_ucut; int icut = s_icut;
  unsigned char* need = (unsigned char*)(ws + OFF_NEED);
  for (unsigned j = t; j < nc; j += 256) {
    unsigned v = cand[j].x; int i = (int)cand[j].y;
    if (v < ucut || (v == ucut && i <= icut)) {
      unsigned slot = atomicAdd(&ctrl[1], 1u);
      if (slot < MAXSEL) {
        ((int*)(ws + OFF_SELL))[slot] = i;
        int b = i / M_; int m = i - b * M_;
        need[b * 4096 + m / 42] = 1;
      }
    }
  }
  __syncthreads();
  // slot assignment over all 32768 pixel-images (need bits from k2w + above)
  int* slotmap = (int*)(ws + OFF_SLOT);
  int* plist = (int*)(ws + OFF_PLIST);
  for (int j = t; j < 32768; j += 256) {
    if (need[j]) {
      unsigned slot = atomicAdd(&s_np, 1u);
      if (slot < MAXPIX) { slotmap[j] = (int)slot; plist[slot] = j; }
      else slotmap[j] = -1;
    }
  }
  __syncthreads();
  if (t == 0) ctrl[2] = s_np;
}

// ---------------- K4c: im2col for needed pixels ----------------
__global__ void __launch_bounds__(256) k4c_im2col(const float* __restrict__ fm, char* ws) {
  unsigned* ctrl = (unsigned*)(ws + OFF_CTRL);
  int npix = min((int)ctrl[2], MAXPIX);
  int blk = blockIdx.x;
  if (blk >= npix) return;
  int pixg = ((const int*)(ws + OFF_PLIST))[blk];
  int b = pixg >> 12, pix = pixg & 4095;
  int y = pix >> 6, x = pix & 63;
  float* Ap = (float*)(ws + OFF_APATCH) + (size_t)blk * KK;
  for (int idx = threadIdx.x; idx < KK; idx += 256) {
    int ic = idx / 9, r = idx - ic * 9;
    int dy = r / 3, dx = r - dy * 3;
    int yy = y + dy - 1, xx = x + dx - 1;
    float v = 0.f;
    if (yy >= 0 && yy < 64 && xx >= 0 && xx < 64)
      v = fm[(((size_t)b * CIN + ic) * 64 + yy) * 64 + xx];
    Ap[idx] = v;
  }
}

// ---------------- K5: sparse conv1 tiled GEMM, partial-sum stores (no atomics) ----------------
// tile 64px x 64oc, K-split 4 (KCH=576), kstep 16, double-buffered LDS.
constexpr int KSPL = 4, KCH = KK / KSPL;     // 576
constexpr int NST = KCH / 16;                // 36 stages

__global__ void __launch_bounds__(256) k5_gemm(const float* __restrict__ w1, char* ws) {
  unsigned* ctrl = (unsigned*)(ws + OFF_CTRL);
  int npix = min((int)ctrl[2], MAXPIX);
  int bid = blockIdx.x;
  int strip = bid & 15, r2 = bid >> 4;
  int och = r2 & 7, ks = r2 >> 3;
  int px0 = strip * 64;
  if (px0 >= npix) return;
  int oc0 = och * 64, kb = ks * KCH;
  __shared__ float As[2][16][64];
  __shared__ float Wsm[2][16][64];
  const float* Ap = (const float*)(ws + OFF_APATCH);
  int t = threadIdx.x;
  int ls = t & 63, kc = t >> 6;         // staging: 64 cols x 4 k-rows (float4 each)
  int tx = t & 15, ty = t >> 4;         // compute: px=px0+tx*4.., oc=oc0+ty*4..
  bool pxok = (px0 + ls) < npix;
  const float* Ag = Ap + (size_t)(px0 + ls) * KK + kb + kc * 4;
  const float* Wg = w1 + (size_t)(oc0 + ls) * KK + kb + kc * 4;
  float4 av = pxok ? *(const float4*)Ag : float4{0.f, 0.f, 0.f, 0.f};
  float4 wv = *(const float4*)Wg;
  As[0][kc * 4 + 0][ls] = av.x; As[0][kc * 4 + 1][ls] = av.y;
  As[0][kc * 4 + 2][ls] = av.z; As[0][kc * 4 + 3][ls] = av.w;
  Wsm[0][kc * 4 + 0][ls] = wv.x; Wsm[0][kc * 4 + 1][ls] = wv.y;
  Wsm[0][kc * 4 + 2][ls] = wv.z; Wsm[0][kc * 4 + 3][ls] = wv.w;
  float acc[4][4] = {};
  __syncthreads();
  for (int s = 0; s < NST; s++) {
    int cur = s & 1;
    float4 an = {0.f, 0.f, 0.f, 0.f}, wn = {0.f, 0.f, 0.f, 0.f};
    bool more = (s + 1 < NST);
    if (more) {
      if (pxok) an = *(const float4*)(Ag + (s + 1) * 16);
      wn = *(const float4*)(Wg + (s + 1) * 16);
    }
#pragma unroll
    for (int k = 0; k < 16; k++) {
      float4 a4 = *(const float4*)&As[cur][k][tx * 4];
      float4 w4 = *(const float4*)&Wsm[cur][k][ty * 4];
      acc[0][0] += w4.x * a4.x; acc[0][1] += w4.x * a4.y;
      acc[0][2] += w4.x * a4.z; acc[0][3] += w4.x * a4.w;
      acc[1][0] += w4.y * a4.x; acc[1][1] += w4.y * a4.y;
      acc[1][2] += w4.y * a4.z; acc[1][3] += w4.y * a4.w;
      acc[2][0] += w4.z * a4.x; acc[2][1] += w4.z * a4.y;
      acc[2][2] += w4.z * a4.z; acc[2][3] += w4.z * a4.w;
      acc[3][0] += w4.w * a4.x; acc[3][1] += w4.w * a4.y;
      acc[3][2] += w4.w * a4.z; acc[3][3] += w4.w * a4.w;
    }
    if (more) {
      int nxt = cur ^ 1;
      As[nxt][kc * 4 + 0][ls] = an.x; As[nxt][kc * 4 + 1][ls] = an.y;
      As[nxt][kc * 4 + 2][ls] = an.z; As[nxt][kc * 4 + 3][ls] = an.w;
      Wsm[nxt][kc * 4 + 0][ls] = wn.x; Wsm[nxt][kc * 4 + 1][ls] = wn.y;
      Wsm[nxt][kc * 4 + 2][ls] = wn.z; Wsm[nxt][kc * 4 + 3][ls] = wn.w;
    }
    __syncthreads();
  }
  float* part = (float*)(ws + OFF_PART) + (size_t)ks * MAXPIX * HIDN;
#pragma unroll
  for (int j = 0; j < 4; j++) {
    int px = px0 + tx * 4 + j;
    if (px < npix) {
      float4 v = {acc[0][j], acc[1][j], acc[2][j], acc[3][j]};
      *(float4*)&part[(size_t)px * HIDN + oc0 + ty * 4] = v;
    }
  }
}

// ---------------- K5r: reduce K-split partials + bias + relu ----------------
__global__ void __launch_bounds__(256) k5r_reduce(const float* __restrict__ b1, char* ws) {
  unsigned* ctrl = (unsigned*)(ws + OFF_CTRL);
  int npix = min((int)ctrl[2], MAXPIX);
  int id = blockIdx.x * 256 + threadIdx.x;
  int px = id >> 9, oc = id & 511;
  if (px >= npix) return;
  const float* part = (const float*)(ws + OFF_PART);
  size_t o = (size_t)px * HIDN + oc;
  float s = part[o];
  s += part[o + (size_t)1 * MAXPIX * HIDN];
  s += part[o + (size_t)2 * MAXPIX * HIDN];
  s += part[o + (size_t)3 * MAXPIX * HIDN];
  s += b1[oc];
  ((float*)(ws + OFF_HID))[o] = s > 0.f ? s : 0.f;
}

// ---------------- K6: heads + loss + finalize ----------------
__global__ void __launch_bounds__(256) k6_head(const float* __restrict__ gt,
                                               const float* __restrict__ cw,
                                               const float* __restrict__ cb,
                                               const float* __restrict__ rw,
                                               const float* __restrict__ rb,
                                               char* ws, float* out) {
  __shared__ float sbase[168], sg[640];
  int t = threadIdx.x;
  fill_base(sbase);
  if (t < 160) {
#pragma clang fp contract(off)
    float g4[4];
    for (int d = 0; d < 4; d++) {
      float v = gt[t * 4 + d];
      g4[d] = (v == -1.0f) ? -1.0f : v * 0.0625f;
    }
    if (!(g4[0] >= 0.0f)) { g4[0] = 0.f; g4[1] = 0.f; g4[2] = 1.f; g4[3] = 1.f; }
    sg[t * 4 + 0] = g4[0]; sg[t * 4 + 1] = g4[1]; sg[t * 4 + 2] = g4[2]; sg[t * 4 + 3] = g4[3];
  }
  __syncthreads();
  unsigned* ctrl = (unsigned*)(ws + OFF_CTRL);
  float* accum = (float*)(ctrl + 16);
  int np = min((int)ctrl[0], MAXPOS);
  int ns = min((int)ctrl[1], MAXSEL);
  int nent = np + ns;
  const unsigned* posl = (const unsigned*)(ws + OFF_POSL);
  const int* sell = (const int*)(ws + OFF_SELL);
  const int* slotmap = (const int*)(ws + OFF_SLOT);
  const float* hid = (const float*)(ws + OFF_HID);
  int lane = t & 63;
  int gwave = blockIdx.x * 4 + (t >> 6);
  int nwaves = gridDim.x * 4;
  for (int e = gwave; e < nent; e += nwaves) {
    bool isPos = e < np;
    int i, arg = 0;
    if (isPos) { unsigned pck = posl[e]; i = (int)(pck & 0x1FFFFFu); arg = (int)(pck >> 21); }
    else i = sell[e - np];
    int b = i / M_; int m = i - b * M_;
    int pix = m / 42; int a = m - pix * 42;
    int y = pix >> 6, x = pix & 63;
    int slot = slotmap[b * 4096 + pix];
    if (slot < 0 || slot >= MAXPIX) continue;
    float h[8];
    const float* hr = hid + (size_t)slot * HIDN;
#pragma unroll
    for (int j = 0; j < 8; j++) h[j] = hr[lane + j * 64];
    const float* cwr = cw + (size_t)a * HIDN;
    float cp = 0.f;
#pragma unroll
    for (int j = 0; j < 8; j++) cp += h[j] * cwr[lane + j * 64];
#pragma unroll
    for (int off = 32; off >= 1; off >>= 1) cp += __shfl_xor(cp, off, 64);
    float conf = cp + cb[a];
    if (isPos) {
      float rp[4];
#pragma unroll
      for (int d = 0; d < 4; d++) {
        const float* rwr = rw + (size_t)(a * 4 + d) * HIDN;
        float sd = 0.f;
#pragma unroll
        for (int j = 0; j < 8; j++) sd += h[j] * rwr[lane + j * 64];
#pragma unroll
        for (int off = 32; off >= 1; off >>= 1) sd += __shfl_xor(sd, off, 64);
        rp[d] = sd + rb[a * 4 + d];
      }
      if (lane == 0) {
#pragma clang fp contract(off)
        float ay0, ax0, ay1, ax1, areaA;
        anchor_box(sbase, a, y, x, ay0, ax0, ay1, ax1, areaA);
        const float* g = sg + (size_t)(b * 20 + arg) * 4;
        float acy = (ay0 + ay1) * 0.5f, acx = (ax0 + ax1) * 0.5f;
        float ah = ay1 - ay0, aw = ax1 - ax0;
        float gcy = (g[0] + g[2]) * 0.5f, gcx = (g[1] + g[3]) * 0.5f;
        float gh = g[2] - g[0], gw = g[3] - g[1];
        float t0 = (gcy - acy) / ah, t1 = (gcx - acx) / aw;
        float t2 = logf(gh / ah), t3 = logf(gw / aw);
        float sL = sl1(rp[0] - t0) + sl1(rp[1] - t1) + sl1(rp[2] - t2) + sl1(rp[3] - t3);
        atomicAdd(&accum[2], sL);
        atomicAdd(&accum[0], softplusf(-conf));
      }
    } else {
      if (lane == 0) atomicAdd(&accum[1], softplusf(conf));
    }
  }
  __syncthreads();
  if (t == 0) {
    __threadfence();
    unsigned done = atomicAdd(&ctrl[10], 1u);
    if (done == gridDim.x - 1) {
      __threadfence();
      float P = (float)min((int)ctrl[0], MAXPOS);
      float S = (float)min((int)ctrl[1], MAXSEL);
      float cls = 0.5f * (accum[0] / P + accum[1] / S);
      out[0] = cls + accum[2] / (P * 4.0f);
    }
  }
}

// ---------------- launcher ----------------
extern "C" void kernel_launch(void* const* d_in, const int* in_sizes, int n_in,
                              void* d_out, int out_size, void* d_ws, size_t ws_size,
                              hipStream_t stream) {
  const float* fm = (const float*)d_in[0];
  const float* gt = (const float*)d_in[1];
  const float* w1 = (const float*)d_in[3];
  const float* b1 = (const float*)d_in[4];
  const float* cw = (const float*)d_in[5];
  const float* cb = (const float*)d_in[6];
  const float* rw = (const float*)d_in[7];
  const float* rb = (const float*)d_in[8];
  char* ws = (char*)d_ws;
  float* out = (float*)d_out;

  hipMemsetAsync(ws, 0, ZERO_END, stream);

  kA<<<HALF / 256, 256, 0, stream>>>(gt, ws);
  dim3 wgrid(K1BLK, B_);
  k2w<<<wgrid, 256, 0, stream>>>(gt, ws);
  kSel<<<1, 256, 0, stream>>>(ws);
  k4c_im2col<<<MAXPIX, 256, 0, stream>>>(fm, ws);
  k5_gemm<<<16 * 8 * KSPL, 256, 0, stream>>>(w1, ws);
  k5r_reduce<<<(MAXPIX * HIDN) / 256, 256, 0, stream>>>(b1, ws);
  k6_head<<<128, 256, 0, stream>>>(gt, cw, cb, rw, rb, ws, out);
}